// Round 1
// baseline (211.780 us; speedup 1.0000x reference)
//
#include <hip/hip_runtime.h>

typedef __attribute__((ext_vector_type(8))) short bf16x8;
typedef __attribute__((ext_vector_type(4))) float f32x4;

__device__ __forceinline__ unsigned short f2bf(float f) {
  union { float f; unsigned u; } a; a.f = f;
  unsigned u = a.u;
  u += 0x7fffu + ((u >> 16) & 1u);   // round-to-nearest-even
  return (unsigned short)(u >> 16);
}

// ---------------------------------------------------------------------------
// Prep: build Bt[tap][n][k] bf16 in workspace.
//   n = opc*4 + q_out  (q minor -> acc regs = quaternion comps)
//   k = c*4   + q_in   (q minor -> float4 input converts to contiguous 8B)
//   Bt = sign[qo][qi] * W_{comp[qo][qi]}[opc][c][tap]
// ---------------------------------------------------------------------------
__global__ void prep_bt(const float* __restrict__ wr, const float* __restrict__ wi,
                        const float* __restrict__ wj, const float* __restrict__ wk,
                        unsigned short* __restrict__ btg) {
  int idx = blockIdx.x * 256 + threadIdx.x;          // 9*256*256 = 589824
  if (idx >= 9 * 256 * 256) return;
  int tap = idx >> 16;
  int rem = idx & 65535;
  int n = rem >> 8, k = rem & 255;
  int opc = n >> 2, qo = n & 3, c = k >> 2, qi = k & 3;
  const int   comp[4][4] = {{0,1,2,3},{1,0,3,2},{2,3,0,1},{3,2,1,0}};
  const float sgn [4][4] = {{1.f,-1.f,-1.f,-1.f},{1.f,1.f,-1.f,1.f},
                            {1.f,1.f,1.f,-1.f},{1.f,-1.f,1.f,1.f}};
  int ci = comp[qo][qi];
  const float* wp = (ci == 0) ? wr : (ci == 1) ? wi : (ci == 2) ? wj : wk;
  float v = sgn[qo][qi] * wp[(opc * 64 + c) * 9 + tap];
  btg[idx] = f2bf(v);
}

// ---------------------------------------------------------------------------
// Main: implicit-GEMM quaternion conv.
// Block: 128 pixels (2 rows of one image) x 128 N. 4 waves, each 64x64.
// K-loop: 4 qc-chunks (16 c each) x 9 taps x 2 k-slices of 32.
// LDS: Xwin[4 rows][66 cols][64 k] bf16 (XOR-swizzled), Btile[128][64] bf16.
// ---------------------------------------------------------------------------
__launch_bounds__(256, 3)
__global__ void qconv_main(const float* __restrict__ x,
                           const unsigned short* __restrict__ btg,
                           const float* __restrict__ bias,
                           float* __restrict__ out) {
  __shared__ char lds[50176];
  char* xwin  = lds;            // 264 rows * 128B = 33792
  char* btile = lds + 33792;    // 128 rows * 128B = 16384

  const int tid  = threadIdx.x;
  const int bid  = blockIdx.x;
  const int nt   = bid & 1;         // N half: n base = nt*128
  const int mt   = bid >> 1;        // 0..511
  const int b    = mt >> 5;
  const int h0   = (mt & 31) * 2;

  const int lane = tid & 63;
  const int wid  = tid >> 6;
  const int wm   = wid & 1;         // which pixel row of the 2
  const int wn   = wid >> 1;        // which 64-wide N half of 128
  const int l15  = lane & 15;
  const int l4   = lane >> 4;

  // zero-fill padding columns 0 and 65 once (never overwritten later)
  if (tid < 64) {
    int hh = tid >> 4, colsel = (tid >> 3) & 1, slot = tid & 7;
    int col = colsel ? 65 : 0;
    f32x4 z = {0.f, 0.f, 0.f, 0.f};
    *reinterpret_cast<f32x4*>(xwin + (hh * 66 + col) * 128 + slot * 16) = z;
  }

  f32x4 acc[4][4];
#pragma unroll
  for (int i = 0; i < 4; ++i)
#pragma unroll
    for (int j = 0; j < 4; ++j)
      acc[i][j] = (f32x4){0.f, 0.f, 0.f, 0.f};

  for (int ch = 0; ch < 4; ++ch) {
    const int c0 = ch * 16;
    __syncthreads();   // protect previous chunk's reads (and zero-fill on ch 0)

    // ---- stage input window: 16 c's x 4 rows x 64 cols, fp32->bf16 ----
#pragma unroll
    for (int i = 0; i < 16; ++i) {
      int u  = i * 256 + tid;
      int w  = u & 63;
      int hh = (u >> 6) & 3;
      int cl = u >> 8;               // 0..15
      int hp = h0 + hh - 1;
      float4 v = make_float4(0.f, 0.f, 0.f, 0.f);
      if (hp >= 0 && hp < 64)
        v = *reinterpret_cast<const float4*>(
              x + (size_t)((((b * 64 + (c0 + cl)) * 64 + hp) * 64 + w) * 4));
      unsigned lo = (unsigned)f2bf(v.x) | ((unsigned)f2bf(v.y) << 16);
      unsigned hi = (unsigned)f2bf(v.z) | ((unsigned)f2bf(v.w) << 16);
      int col  = w + 1;
      int byte = (hh * 66 + col) * 128 + ((cl * 8) ^ ((col & 7) << 4));
      *reinterpret_cast<uint2*>(xwin + byte) = make_uint2(lo, hi);
    }

    for (int tap = 0; tap < 9; ++tap) {
      if (tap) __syncthreads();      // previous tap done reading Btile

      // ---- stage B tile [128 n][64 k] bf16 ----
#pragma unroll
      for (int i = 0; i < 4; ++i) {
        int u = i * 256 + tid;
        int nl = u >> 3, slot = u & 7;
        const unsigned short* src =
            btg + (size_t)((tap * 256 + nt * 128 + nl) * 256 + ch * 64 + slot * 8);
        uint4 vv = *reinterpret_cast<const uint4*>(src);
        int byte = nl * 128 + ((slot * 16) ^ ((nl & 7) << 4));
        *reinterpret_cast<uint4*>(btile + byte) = vv;
      }
      __syncthreads();               // X (tap 0) and B visible

      const int dh = tap / 3 - 1;
      const int dw = tap % 3 - 1;
      const int hh = wm + dh + 1;    // 0..3
      const char* xrow = xwin + (hh * 66) * 128;

#pragma unroll
      for (int ks = 0; ks < 2; ++ks) {
        bf16x8 af[4], bf[4];
#pragma unroll
        for (int fm = 0; fm < 4; ++fm) {
          int col = fm * 16 + l15 + dw + 1;       // 0..65
          int off = col * 128 + ((ks * 64 + l4 * 16) ^ ((col & 7) << 4));
          af[fm] = *reinterpret_cast<const bf16x8*>(xrow + off);
        }
#pragma unroll
        for (int fn = 0; fn < 4; ++fn) {
          int nl  = wn * 64 + fn * 16 + l15;
          int off = nl * 128 + ((ks * 64 + l4 * 16) ^ ((nl & 7) << 4));
          bf[fn] = *reinterpret_cast<const bf16x8*>(btile + off);
        }
#pragma unroll
        for (int fn = 0; fn < 4; ++fn)
#pragma unroll
          for (int fm = 0; fm < 4; ++fm)
            acc[fn][fm] = __builtin_amdgcn_mfma_f32_16x16x32_bf16(
                bf[fn], af[fm], acc[fn][fm], 0, 0, 0);
      }
    }
  }

  // ---- epilogue: reg r == quaternion comp -> one float4 per (pixel,opc) ----
  const int h = h0 + wm;
#pragma unroll
  for (int fn = 0; fn < 4; ++fn) {
    int ng  = nt * 128 + wn * 64 + fn * 16 + l4 * 4;  // multiple of 4
    int opc = ng >> 2;
    float bv = bias[opc];
#pragma unroll
    for (int fm = 0; fm < 4; ++fm) {
      int w = fm * 16 + l15;
      f32x4 v = acc[fn][fm];
      v.x += bv;   // bias only on real component (q = 0)
      *reinterpret_cast<f32x4*>(
          out + (size_t)((((b * 64 + opc) * 64 + h) * 64 + w) * 4)) = v;
    }
  }
}

extern "C" void kernel_launch(void* const* d_in, const int* in_sizes, int n_in,
                              void* d_out, int out_size, void* d_ws, size_t ws_size,
                              hipStream_t stream) {
  const float* x    = (const float*)d_in[0];
  const float* wr   = (const float*)d_in[1];
  const float* wi   = (const float*)d_in[2];
  const float* wj   = (const float*)d_in[3];
  const float* wk   = (const float*)d_in[4];
  const float* bias = (const float*)d_in[5];
  unsigned short* btg = (unsigned short*)d_ws;   // 9*256*256*2 = 1.18 MB

  prep_bt<<<2304, 256, 0, stream>>>(wr, wi, wj, wk, btg);
  qconv_main<<<1024, 256, 0, stream>>>(x, btg, bias, (float*)d_out);
}

// Round 2
// 150.252 us; speedup vs baseline: 1.4095x; 1.4095x over previous
//
#include <hip/hip_runtime.h>

typedef __attribute__((ext_vector_type(8))) short bf16x8;
typedef __attribute__((ext_vector_type(4))) float f32x4;

__device__ __forceinline__ unsigned short f2bf(float f) {
  union { float f; unsigned u; } a; a.f = f;
  unsigned u = a.u;
  u += 0x7fffu + ((u >> 16) & 1u);   // round-to-nearest-even
  return (unsigned short)(u >> 16);
}

// ---------------------------------------------------------------------------
// Prep: build Bt[tap][n][k] bf16 in workspace.
//   n = opc*4 + q_out  (q minor -> acc regs = quaternion comps)
//   k = c*4   + q_in   (q minor -> float4 input converts to contiguous 8B)
// ---------------------------------------------------------------------------
__global__ void prep_bt(const float* __restrict__ wr, const float* __restrict__ wi,
                        const float* __restrict__ wj, const float* __restrict__ wk,
                        unsigned short* __restrict__ btg) {
  int idx = blockIdx.x * 256 + threadIdx.x;          // 9*256*256 = 589824
  if (idx >= 9 * 256 * 256) return;
  int tap = idx >> 16;
  int rem = idx & 65535;
  int n = rem >> 8, k = rem & 255;
  int opc = n >> 2, qo = n & 3, c = k >> 2, qi = k & 3;
  const int   comp[4][4] = {{0,1,2,3},{1,0,3,2},{2,3,0,1},{3,2,1,0}};
  const float sgn [4][4] = {{1.f,-1.f,-1.f,-1.f},{1.f,1.f,-1.f,1.f},
                            {1.f,1.f,1.f,-1.f},{1.f,-1.f,1.f,1.f}};
  int ci = comp[qo][qi];
  const float* wp = (ci == 0) ? wr : (ci == 1) ? wi : (ci == 2) ? wj : wk;
  float v = sgn[qo][qi] * wp[(opc * 64 + c) * 9 + tap];
  btg[idx] = f2bf(v);
}

// ---------------------------------------------------------------------------
// Main: implicit-GEMM quaternion conv.
// Block: 256 pixels (4 image rows) x FULL N=256. 8 waves, each 128px x 64N.
// Grid = 256 blocks = 1 per CU. B loaded per-fragment from L2 (1.18 MB,
// fully resident) -> NO per-tap barriers; 2 barriers per chunk only.
// LDS: Xwin[6 rows][66 cols][64 k] bf16, XOR-swizzled (k ^ (col&7)<<4).
// Async X prefetch: next chunk's 12 float4/thread issued before tap loop.
// ---------------------------------------------------------------------------
__launch_bounds__(512, 2)
__global__ void qconv_main(const float* __restrict__ x,
                           const unsigned short* __restrict__ btg,
                           const float* __restrict__ bias,
                           float* __restrict__ out) {
  __shared__ char xwin[6 * 66 * 128];   // 50688 B

  const int tid = threadIdx.x;
  const int bid = blockIdx.x;
  const int b   = bid >> 4;             // image
  const int h0  = (bid & 15) * 4;       // first image row of this block

  const int lane = tid & 63;
  const int wid  = tid >> 6;            // 0..7
  const int wm   = wid & 1;             // which 2-row pixel half
  const int wn   = wid >> 1;            // 0..3: 64-wide N quarter
  const int l15  = lane & 15;
  const int l4   = lane >> 4;

  const int w_ = tid & 63;              // staging column
  const int rh = tid >> 6;              // staging row-group 0..7

  // zero-fill padding columns 0 and 65 (6 rows x 2 cols x 128 B)
  if (tid < 96) {
    int hh = tid >> 4, colsel = (tid >> 3) & 1, slot = tid & 7;
    int col = colsel ? 65 : 0;
    *reinterpret_cast<f32x4*>(xwin + (hh * 66 + col) * 128 + slot * 16) =
        (f32x4){0.f, 0.f, 0.f, 0.f};
  }

  f32x4 acc[4][8];
#pragma unroll
  for (int i = 0; i < 4; ++i)
#pragma unroll
    for (int j = 0; j < 8; ++j)
      acc[i][j] = (f32x4){0.f, 0.f, 0.f, 0.f};

  float4 xr[12];

  // issue global loads for chunk CH: 16 c x 6 window rows x 64 w
#define LOADX(CH)                                                              \
  do {                                                                         \
    _Pragma("unroll")                                                          \
    for (int i = 0; i < 12; ++i) {                                             \
      int pi = rh * 12 + i;                                                    \
      int hh = pi >> 4, cl = (CH) * 16 + (pi & 15);                            \
      int hp = h0 + hh - 1;                                                    \
      float4 v = make_float4(0.f, 0.f, 0.f, 0.f);                              \
      if (hp >= 0 && hp < 64)                                                  \
        v = *reinterpret_cast<const float4*>(                                  \
            x + (size_t)((((b * 64 + cl) * 64 + hp) * 64 + w_) * 4));          \
      xr[i] = v;                                                               \
    }                                                                          \
  } while (0)

  LOADX(0);

  for (int ch = 0; ch < 4; ++ch) {
    __syncthreads();   // all waves done reading xwin of previous chunk

    // convert + write staged chunk into LDS
#pragma unroll
    for (int i = 0; i < 12; ++i) {
      int pi = rh * 12 + i;
      int hh = pi >> 4, cl = pi & 15;
      unsigned lo = (unsigned)f2bf(xr[i].x) | ((unsigned)f2bf(xr[i].y) << 16);
      unsigned hi = (unsigned)f2bf(xr[i].z) | ((unsigned)f2bf(xr[i].w) << 16);
      int col  = w_ + 1;
      int byte = (hh * 66 + col) * 128 + ((cl * 8) ^ ((col & 7) << 4));
      *reinterpret_cast<uint2*>(xwin + byte) = make_uint2(lo, hi);
    }
    __syncthreads();   // xwin ready

    if (ch < 3) LOADX(ch + 1);   // overlap next chunk's HBM reads with taps

    const unsigned short* bbase =
        btg + (size_t)(wn * 64 + l15) * 256 + ch * 64 + l4 * 8;

#pragma unroll
    for (int tap = 0; tap < 9; ++tap) {
      const int dh = tap / 3 - 1;
      const int dw = tap % 3 - 1;
#pragma unroll
      for (int ks = 0; ks < 2; ++ks) {
        bf16x8 bfv[4];
#pragma unroll
        for (int fn = 0; fn < 4; ++fn)
          bfv[fn] = *reinterpret_cast<const bf16x8*>(
              bbase + tap * 65536 + fn * 4096 + ks * 32);
        bf16x8 afv[8];
#pragma unroll
        for (int fm = 0; fm < 8; ++fm) {
          int hh  = wm * 2 + (fm >> 2) + dh + 1;         // 0..5
          int col = (fm & 3) * 16 + l15 + dw + 1;        // 0..65
          int off = (hh * 66 + col) * 128 +
                    ((ks * 64 + l4 * 16) ^ ((col & 7) << 4));
          afv[fm] = *reinterpret_cast<const bf16x8*>(xwin + off);
        }
        __builtin_amdgcn_s_setprio(1);
#pragma unroll
        for (int fn = 0; fn < 4; ++fn)
#pragma unroll
          for (int fm = 0; fm < 8; ++fm)
            acc[fn][fm] = __builtin_amdgcn_mfma_f32_16x16x32_bf16(
                bfv[fn], afv[fm], acc[fn][fm], 0, 0, 0);
        __builtin_amdgcn_s_setprio(0);
      }
    }
  }

  // epilogue: acc reg r == quaternion comp -> one float4 per (pixel,opc)
#pragma unroll
  for (int fn = 0; fn < 4; ++fn) {
    int opc = wn * 16 + fn * 4 + l4;
    float bv = bias[opc];
#pragma unroll
    for (int fm = 0; fm < 8; ++fm) {
      int h = h0 + wm * 2 + (fm >> 2);
      int w = (fm & 3) * 16 + l15;
      f32x4 v = acc[fn][fm];
      v.x += bv;   // bias only on real component
      *reinterpret_cast<f32x4*>(
          out + (size_t)((((b * 64 + opc) * 64 + h) * 64 + w) * 4)) = v;
    }
  }
#undef LOADX
}

extern "C" void kernel_launch(void* const* d_in, const int* in_sizes, int n_in,
                              void* d_out, int out_size, void* d_ws, size_t ws_size,
                              hipStream_t stream) {
  const float* x    = (const float*)d_in[0];
  const float* wr   = (const float*)d_in[1];
  const float* wi   = (const float*)d_in[2];
  const float* wj   = (const float*)d_in[3];
  const float* wk   = (const float*)d_in[4];
  const float* bias = (const float*)d_in[5];
  unsigned short* btg = (unsigned short*)d_ws;   // 9*256*256*2 = 1.18 MB

  prep_bt<<<2304, 256, 0, stream>>>(wr, wi, wj, wk, btg);
  qconv_main<<<256, 512, 0, stream>>>(x, btg, bias, (float*)d_out);
}

// Round 3
// 114.766 us; speedup vs baseline: 1.8453x; 1.3092x over previous
//
#include <hip/hip_runtime.h>

typedef __attribute__((ext_vector_type(8))) short bf16x8;
typedef __attribute__((ext_vector_type(4))) float f32x4;
typedef __attribute__((ext_vector_type(16))) float f32x16;

__device__ __forceinline__ unsigned short f2bf(float f) {
  union { float f; unsigned u; } a; a.f = f;
  unsigned u = a.u;
  u += 0x7fffu + ((u >> 16) & 1u);   // round-to-nearest-even
  return (unsigned short)(u >> 16);
}

// ---------------------------------------------------------------------------
// Prep: build Bt[tap][n][k] bf16 in workspace.
//   n = opc*4 + q_out  (q minor -> acc regs = quaternion comps)
//   k = c*4   + q_in   (q minor -> float4 input converts to contiguous 8B)
// ---------------------------------------------------------------------------
__global__ void prep_bt(const float* __restrict__ wr, const float* __restrict__ wi,
                        const float* __restrict__ wj, const float* __restrict__ wk,
                        unsigned short* __restrict__ btg) {
  int idx = blockIdx.x * 256 + threadIdx.x;          // 9*256*256 = 589824
  if (idx >= 9 * 256 * 256) return;
  int tap = idx >> 16;
  int rem = idx & 65535;
  int n = rem >> 8, k = rem & 255;
  int opc = n >> 2, qo = n & 3, c = k >> 2, qi = k & 3;
  const int   comp[4][4] = {{0,1,2,3},{1,0,3,2},{2,3,0,1},{3,2,1,0}};
  const float sgn [4][4] = {{1.f,-1.f,-1.f,-1.f},{1.f,1.f,-1.f,1.f},
                            {1.f,1.f,1.f,-1.f},{1.f,-1.f,1.f,1.f}};
  int ci = comp[qo][qi];
  const float* wp = (ci == 0) ? wr : (ci == 1) ? wi : (ci == 2) ? wj : wk;
  float v = sgn[qo][qi] * wp[(opc * 64 + c) * 9 + tap];
  btg[idx] = f2bf(v);
}

// ---------------------------------------------------------------------------
// Main: implicit-GEMM quaternion conv, 32x32x16 MFMA.
// Block: 256 threads = 4 waves; tile = 128 px (2 image rows) x 256 N.
// Wave w = all 128 px x N quarter [w*64, w*64+64).
// Grid 512 = 2 blocks/CU -> cross-block overlap of staging vs MFMA.
// Weights double-buffered in registers per tap (L2-resident btg).
// LDS: Xwin[4 rows][66 cols][64 k] bf16, XOR-swizzled.
// ---------------------------------------------------------------------------
__launch_bounds__(256, 2)
__global__ void qconv_main(const float* __restrict__ x,
                           const unsigned short* __restrict__ btg,
                           const float* __restrict__ bias,
                           float* __restrict__ out) {
  __shared__ char xwin[4 * 66 * 128];   // 33792 B

  const int tid = threadIdx.x;
  // XCD-aware swizzle (512 blocks, 8 XCDs -> 64 consecutive per XCD)
  const int nb  = (blockIdx.x & 7) * 64 + (blockIdx.x >> 3);
  const int b   = nb >> 5;              // image
  const int h0  = (nb & 31) * 2;        // first of 2 image rows

  const int lane = tid & 63;
  const int wn   = tid >> 6;            // 0..3: N quarter
  const int l31  = lane & 31;
  const int l32  = lane >> 5;

  const int w_ = tid & 63;              // staging column
  // zero-fill padding columns 0 and 65 (4 rows x 2 cols x 8 slots)
  if (tid < 64) {
    int hh = tid >> 4, colsel = (tid >> 3) & 1, slot = tid & 7;
    int col = colsel ? 65 : 0;
    *reinterpret_cast<f32x4*>(xwin + (hh * 66 + col) * 128 + slot * 16) =
        (f32x4){0.f, 0.f, 0.f, 0.f};
  }

  f32x16 acc[2][4];
#pragma unroll
  for (int i = 0; i < 2; ++i)
#pragma unroll
    for (int j = 0; j < 4; ++j)
      acc[i][j] = (f32x16)(0.f);

  for (int ch = 0; ch < 4; ++ch) {
    __syncthreads();   // previous chunk fully consumed (and pad-fill on ch 0)

    // ---- stage input window: 16 c x 4 rows x 64 cols, fp32 -> bf16 ----
#pragma unroll
    for (int i = 0; i < 16; ++i) {
      int u  = i * 256 + tid;
      int hh = (u >> 6) & 3;
      int cl = u >> 8;                     // 0..15
      int hp = h0 + hh - 1;
      float4 v = make_float4(0.f, 0.f, 0.f, 0.f);
      if (hp >= 0 && hp < 64)
        v = *reinterpret_cast<const float4*>(
            x + (size_t)((((b * 64 + (ch * 16 + cl)) * 64 + hp) * 64 + w_) * 4));
      unsigned lo = (unsigned)f2bf(v.x) | ((unsigned)f2bf(v.y) << 16);
      unsigned hi = (unsigned)f2bf(v.z) | ((unsigned)f2bf(v.w) << 16);
      int col  = w_ + 1;
      int byte = (hh * 66 + col) * 128 + ((cl * 8) ^ ((col & 7) << 4));
      *reinterpret_cast<uint2*>(xwin + byte) = make_uint2(lo, hi);
    }
    __syncthreads();   // xwin ready

    // per-wave weight base: n = wn*64 + fn*32 + l31, k = ch*64 + kst*16 + l32*8
    const unsigned short* wb =
        btg + (size_t)(wn * 64 + l31) * 256 + ch * 64 + l32 * 8;

    bf16x8 wf[2][8];   // [buf][kst*2+fn] weight fragments, double-buffered
#pragma unroll
    for (int f = 0; f < 8; ++f)
      wf[0][f] = *reinterpret_cast<const bf16x8*>(
          wb + (f & 1) * 8192 + (f >> 1) * 16);

#pragma unroll
    for (int tap = 0; tap < 9; ++tap) {
      const int cur = tap & 1;
      if (tap < 8) {
#pragma unroll
        for (int f = 0; f < 8; ++f)
          wf[cur ^ 1][f] = *reinterpret_cast<const bf16x8*>(
              wb + (tap + 1) * 65536 + (f & 1) * 8192 + (f >> 1) * 16);
      }
      const int dh = tap / 3 - 1;
      const int dw = tap % 3 - 1;
#pragma unroll
      for (int kst = 0; kst < 4; ++kst) {
        bf16x8 pf[4];
#pragma unroll
        for (int fm = 0; fm < 4; ++fm) {
          int pix = fm * 32 + l31;
          int wc  = (pix & 63) + dw + 1;            // 0..65
          int hh  = (pix >> 6) + dh + 1;            // 0..3
          int off = (hh * 66 + wc) * 128 +
                    ((kst * 32 + l32 * 16) ^ ((wc & 7) << 4));
          pf[fm] = *reinterpret_cast<const bf16x8*>(xwin + off);
        }
        __builtin_amdgcn_s_setprio(1);
#pragma unroll
        for (int fn = 0; fn < 2; ++fn)
#pragma unroll
          for (int fm = 0; fm < 4; ++fm)
            acc[fn][fm] = __builtin_amdgcn_mfma_f32_32x32x16_bf16(
                wf[cur][kst * 2 + fn], pf[fm], acc[fn][fm], 0, 0, 0);
        __builtin_amdgcn_s_setprio(0);
      }
    }
  }

  // ---- epilogue: D row=(reg&3)+8*(reg>>2)+4*l32 -> reg&3 == q component ----
#pragma unroll
  for (int fn = 0; fn < 2; ++fn) {
#pragma unroll
    for (int fm = 0; fm < 4; ++fm) {
      int pix = fm * 32 + l31;
      int w   = pix & 63;
      int h   = h0 + (pix >> 6);
#pragma unroll
      for (int g = 0; g < 4; ++g) {
        int opc = wn * 16 + fn * 8 + g * 2 + l32;
        f32x4 v = {acc[fn][fm][4 * g + 0], acc[fn][fm][4 * g + 1],
                   acc[fn][fm][4 * g + 2], acc[fn][fm][4 * g + 3]};
        v.x += bias[opc];   // bias only on real component
        *reinterpret_cast<f32x4*>(
            out + (size_t)((((b * 64 + opc) * 64 + h) * 64 + w) * 4)) = v;
      }
    }
  }
}

extern "C" void kernel_launch(void* const* d_in, const int* in_sizes, int n_in,
                              void* d_out, int out_size, void* d_ws, size_t ws_size,
                              hipStream_t stream) {
  const float* x    = (const float*)d_in[0];
  const float* wr   = (const float*)d_in[1];
  const float* wi   = (const float*)d_in[2];
  const float* wj   = (const float*)d_in[3];
  const float* wk   = (const float*)d_in[4];
  const float* bias = (const float*)d_in[5];
  unsigned short* btg = (unsigned short*)d_ws;   // 9*256*256*2 = 1.18 MB

  prep_bt<<<2304, 256, 0, stream>>>(wr, wi, wj, wk, btg);
  qconv_main<<<512, 256, 0, stream>>>(x, btg, bias, (float*)d_out);
}